// Round 11
// baseline (35.733 us; speedup 1.0000x reference)
//
#include <hip/hip_runtime.h>
#include <math.h>

#define KK 20
#define NPTS 8192
#define NQB 16              // queries per block
#define QPL 8               // queries per lane
#define NCH 256             // chunks per query (32 pts each, strided across windows)
#define THREADS 512
#define WIN 2048            // points per staged LDS window
#define NWIN 4
#define JPW (WIN / NCH)     // 8 candidates per chunk per window
#define PPT (WIN / THREADS) // 4 points staged per thread
#define CAP 64              // hit buffer capacity per query
#define MAXC 64             // candidate-chunk list capacity per query
#define MARGIN 4e-3f        // >> 2*max|d_fast - d_exact| (fp32 fma vs split)

// Exact (non-contracted) IEEE ops matching the NumPy reference bit-for-bit.
// np.sum (pairwise, n<8) accumulates ascending: (x^2 + y^2) + z^2.
__device__ __forceinline__ float norm3(float x, float y, float z) {
    return __fadd_rn(__fadd_rn(__fmul_rn(x, x), __fmul_rn(y, y)), __fmul_rn(z, z));
}

// np.einsum (optimize=False) remainder falls through DESCENDING for count=3:
// ((z*z') + y*y') + x*x'.  dist = ((-2*dot) + n_src) + n_dst.
__device__ __forceinline__ float dist_exact(float px, float py, float pz, float pw,
                                            float qx, float qy, float qz, float qn) {
    const float dot = __fadd_rn(
        __fadd_rn(__fmul_rn(pz, qz), __fmul_rn(py, qy)), __fmul_rn(px, qx));
    return __fadd_rn(__fadd_rn(__fmul_rn(dot, -2.0f), pw), qn);
}

extern "C" __global__ __launch_bounds__(THREADS, 4)
void knn_kernel(const float* __restrict__ verts, int* __restrict__ out)
{
    // Static LDS ~62.7 KB -> 2 blocks/CU, grid 512 = exactly 2/CU.
    __shared__ float4 pts[WIN];                 // 32768 B
    __shared__ float  vdump[NCH][NQB + 1];      // 17408 B
    __shared__ float  hbd[NQB][CAP];            //  4096 B
    __shared__ int    hbi[NQB][CAP];            //  4096 B
    __shared__ int    cand[NQB][MAXC];          //  4096 B
    __shared__ float  Tq[NQB];
    __shared__ int    cnt[NQB];
    __shared__ int    cnt2[NQB];

    const int t    = threadIdx.x;
    const int lane = t & 63;
    const int wv   = t >> 6;          // wave 0..7
    const int c    = t >> 1;          // chunk 0..255
    const int qh   = t & 1;           // query group 0..1
    const int xr   = c & 7;           // read-order stagger (JPW=8)
    const int qbase = blockIdx.x * NQB + qh * QPL;

    if (t < NQB) { cnt[t] = 0; cnt2[t] = 0; }

    // Register tile: 8 queries per lane. Fast path uses folded -2*q coords and
    // OMITS qn inside the min (constant shift per query, re-added once).
    float qx2[QPL], qy2[QPL], qz2[QPL], qn[QPL];
#pragma unroll
    for (int i = 0; i < QPL; ++i) {
        const float x = verts[(qbase + i) * 3 + 0];
        const float y = verts[(qbase + i) * 3 + 1];
        const float z = verts[(qbase + i) * 3 + 2];
        qn[i] = norm3(x, y, z);
        qx2[i] = -2.0f * x; qy2[i] = -2.0f * y; qz2[i] = -2.0f * z;
    }

    // Issue-early / commit-late staging (T14).
    float sx[PPT], sy[PPT], sz[PPT];
    auto issue = [&](int w) {
#pragma unroll
        for (int i = 0; i < PPT; ++i) {
            const int n = w * WIN + i * THREADS + t;
            sx[i] = verts[n * 3 + 0];
            sy[i] = verts[n * 3 + 1];
            sz[i] = verts[n * 3 + 2];
        }
    };
    auto commit = [&]() {
#pragma unroll
        for (int i = 0; i < PPT; ++i) {
            const int m = i * THREADS + t;
            pts[m] = make_float4(sx[i], sy[i], sz[i], norm3(sx[i], sy[i], sz[i]));
        }
    };

    // ---------------- PASS 1: per-(chunk,query) MIN (shifted fast dist) -----
    // Chunk c's point set: { w*WIN + c*JPW + j : w in [0,NWIN), j in [0,JPW) }.
    float mn[QPL];
#pragma unroll
    for (int i = 0; i < QPL; ++i) mn[i] = INFINITY;

    issue(0); commit(); __syncthreads();
#pragma unroll 1
    for (int w = 0; w < NWIN; ++w) {
        if (w + 1 < NWIN) issue(w + 1);
#pragma unroll
        for (int v = 0; v < JPW; ++v) {
            const float4 p = pts[c * JPW + (v ^ xr)];
#pragma unroll
            for (int i = 0; i < QPL; ++i) {
                const float d = __builtin_fmaf(p.x, qx2[i],
                                __builtin_fmaf(p.y, qy2[i],
                                __builtin_fmaf(p.z, qz2[i], p.w)));
                mn[i] = fminf(mn[i], d);
            }
        }
        __syncthreads();
        if (w + 1 < NWIN) { commit(); __syncthreads(); }
        // window 3 stays resident for pass 2
    }

    // Re-add qn so vdump holds true fast distances (comparable to exact + T).
#pragma unroll
    for (int i = 0; i < QPL; ++i) {
        mn[i] += qn[i];
        vdump[c][qh * QPL + i] = mn[i];
    }
    __syncthreads();

    issue(0);   // pass-2 prefetch of window 0 hides under the merge phase

    // ------- T' = 20th smallest of 256 chunk-minima + margin ----------------
    // Wave wv handles queries {2wv, 2wv+1}: 256-elem bitonic, 4 regs/lane
    // (element index = lane*4 + reg; verified in R7).
#pragma unroll
    for (int r = 0; r < 2; ++r) {
        const int qq = wv * 2 + r;
        float r0 = vdump[lane * 4 + 0][qq];
        float r1 = vdump[lane * 4 + 1][qq];
        float r2 = vdump[lane * 4 + 2][qq];
        float r3 = vdump[lane * 4 + 3][qq];
        { const float lo = fminf(r0, r1), hi = fmaxf(r0, r1); r0 = lo; r1 = hi; }
        { const float lo = fminf(r2, r3), hi = fmaxf(r2, r3); r2 = hi; r3 = lo; }
#pragma unroll
        for (int k = 4; k <= 256; k <<= 1) {
            const bool asc = (((lane << 2) & k) == 0);
#pragma unroll
            for (int j = k >> 1; j >= 4; j >>= 1) {
                const int lj = j >> 2;
                const bool lower = ((lane & lj) == 0);
                const bool keepmin = (lower == asc);
                const float o0 = __shfl_xor(r0, lj), o1 = __shfl_xor(r1, lj);
                const float o2 = __shfl_xor(r2, lj), o3 = __shfl_xor(r3, lj);
                r0 = keepmin ? fminf(r0, o0) : fmaxf(r0, o0);
                r1 = keepmin ? fminf(r1, o1) : fmaxf(r1, o1);
                r2 = keepmin ? fminf(r2, o2) : fmaxf(r2, o2);
                r3 = keepmin ? fminf(r3, o3) : fmaxf(r3, o3);
            }
            {   // j = 2: (r0,r2), (r1,r3)
                const float lo0 = fminf(r0, r2), hi0 = fmaxf(r0, r2);
                const float lo1 = fminf(r1, r3), hi1 = fmaxf(r1, r3);
                r0 = asc ? lo0 : hi0; r2 = asc ? hi0 : lo0;
                r1 = asc ? lo1 : hi1; r3 = asc ? hi1 : lo1;
            }
            {   // j = 1: (r0,r1), (r2,r3)
                const float lo0 = fminf(r0, r1), hi0 = fmaxf(r0, r1);
                const float lo1 = fminf(r2, r3), hi1 = fmaxf(r2, r3);
                r0 = asc ? lo0 : hi0; r1 = asc ? hi0 : lo0;
                r2 = asc ? lo1 : hi1; r3 = asc ? hi1 : lo1;
            }
        }
        const float T = __shfl(r3, 4);          // element 19 = lane 4, reg 3
        if (lane == 0) Tq[qq] = T + MARGIN;
    }
    __syncthreads();

    // ------- Candidate chunks: every chunk that could hold a top-20 ---------
#pragma unroll
    for (int i = 0; i < QPL; ++i) {
        const int q = qh * QPL + i;
        if (mn[i] <= Tq[q]) {
            const int e = atomicAdd(&cnt2[q], 1);
            if (e < MAXC) cand[q][e] = c;
        }
    }
    __syncthreads();

    // ------- PASS 2 (sparse, from LDS): exact dists in candidate chunks -----
    // Wave wv owns queries {2wv, 2wv+1}. Per wave-read: 8 candidates x 8 pts
    // (lane>>3 = candidate, lane&7 = point) -> fully distinct rows, no conflicts.
    auto scanwin = [&](int w) {
#pragma unroll
        for (int r = 0; r < 2; ++r) {
            const int qq = wv * 2 + r;
            const int qg2 = blockIdx.x * NQB + qq;
            const float qxe = verts[qg2 * 3 + 0];
            const float qye = verts[qg2 * 3 + 1];
            const float qze = verts[qg2 * 3 + 2];
            const float qne = norm3(qxe, qye, qze);
            const float T = Tq[qq];
            const int nc = min(cnt2[qq], MAXC);
            const int j = lane & 7;
            for (int e0 = 0; e0 < nc; e0 += 8) {    // wave-uniform
                const int e = e0 + (lane >> 3);
                const bool val = e < nc;
                const int cc = cand[qq][val ? e : 0];
                const float4 p = pts[cc * JPW + j];
                const float pw = norm3(p.x, p.y, p.z);
                const float d = dist_exact(p.x, p.y, p.z, pw, qxe, qye, qze, qne);
                if (val && d <= T) {
                    const int slot = atomicAdd(&cnt[qq], 1);
                    if (slot < CAP) {
                        hbd[qq][slot] = d;
                        hbi[qq][slot] = w * WIN + cc * JPW + j;
                    }
                }
            }
        }
    };

    scanwin(NWIN - 1);          // window 3 still resident from pass 1
    __syncthreads();
    commit();                   // window 0 (issued before the merge)
    __syncthreads();
#pragma unroll 1
    for (int ww = 0; ww < NWIN - 1; ++ww) {     // windows 0,1,2
        if (ww + 1 < NWIN - 1) issue(ww + 1);
        scanwin(ww);
        __syncthreads();
        if (ww + 1 < NWIN - 1) { commit(); __syncthreads(); }
    }
    __syncthreads();

    // ------- Final: exact stable top-20 via u64 bitonic ---------------------
#pragma unroll
    for (int r = 0; r < 2; ++r) {
        const int qq = wv * 2 + r;
        const int kc = min(cnt[qq], CAP);       // kc >= 20 guaranteed
        unsigned long long key = ~0ULL;
        if (lane < kc) {
            const float d = hbd[qq][lane];
            unsigned u = __float_as_uint(d);
            u ^= ((unsigned)((int)u >> 31)) | 0x80000000u;   // order-preserving map
            key = ((unsigned long long)u << 32) | (unsigned)hbi[qq][lane];
        }
#pragma unroll
        for (int k = 2; k <= 64; k <<= 1) {
#pragma unroll
            for (int j = k >> 1; j >= 1; j >>= 1) {
                const unsigned long long o = __shfl_xor(key, j);
                const bool asc = ((lane & k) == 0);
                const bool lower = ((lane & j) == 0);
                const bool keepmin = (lower == asc);
                const bool lt = key < o;
                key = (keepmin == lt) ? key : o;
            }
        }
        if (lane < KK)
            out[(blockIdx.x * NQB + qq) * KK + lane] =
                (int)(unsigned)(key & 0xffffffffULL);
    }
}

extern "C" void kernel_launch(void* const* d_in, const int* in_sizes, int n_in,
                              void* d_out, int out_size, void* d_ws, size_t ws_size,
                              hipStream_t stream) {
    // d_in[0] = feats (unused). d_in[1] = vertices [4,8192,3] f32; batch 0 only.
    const float* verts = (const float*)d_in[1];
    int* out = (int*)d_out;
    knn_kernel<<<dim3(NPTS / NQB), dim3(THREADS), 0, stream>>>(verts, out);
}

// Round 12
// 32.872 us; speedup vs baseline: 1.0870x; 1.0870x over previous
//
#include <hip/hip_runtime.h>
#include <math.h>

#define KK 20
#define NPTS 8192
#define NQB 16              // queries per block
#define QPL 8               // queries per lane (pass 1)
#define NCH 256             // chunks per query (32 pts each, strided across windows)
#define THREADS 512
#define WIN 2048            // points per staged LDS window
#define NWIN 4
#define JPW (WIN / NCH)     // 8 candidates per chunk per window
#define CAP 64              // hit buffer capacity per query
#define MAXC 64             // candidate-chunk list capacity per query
#define MARGIN 4e-3f        // >> 2*max|d_fast - d_exact|

// Exact (non-contracted) IEEE ops matching the NumPy reference bit-for-bit.
// np.sum (pairwise, n<8) accumulates ascending: (x^2 + y^2) + z^2.
__device__ __forceinline__ float norm3(float x, float y, float z) {
    return __fadd_rn(__fadd_rn(__fmul_rn(x, x), __fmul_rn(y, y)), __fmul_rn(z, z));
}

// np.einsum (optimize=False) remainder falls through DESCENDING for count=3:
// ((z*z') + y*y') + x*x'.  dist = ((-2*dot) + n_src) + n_dst.
__device__ __forceinline__ float dist_exact(float px, float py, float pz, float pw,
                                            float qx, float qy, float qz, float qn) {
    const float dot = __fadd_rn(
        __fadd_rn(__fmul_rn(pz, qz), __fmul_rn(py, qy)), __fmul_rn(px, qx));
    return __fadd_rn(__fadd_rn(__fmul_rn(dot, -2.0f), pw), qn);
}

extern "C" __global__ __launch_bounds__(THREADS, 4)
void knn_kernel(const float* __restrict__ verts, int* __restrict__ out)
{
    // Static LDS 62656 B -> 2 blocks/CU, grid 512 = exactly 2/CU.
    __shared__ float4 pts[WIN];                 // 32768 B
    __shared__ float  vdump[NCH][NQB + 1];      // 17408 B
    __shared__ float  hbd[NQB][CAP];            //  4096 B
    __shared__ int    hbi[NQB][CAP];            //  4096 B
    __shared__ int    cand[NQB][MAXC];          //  4096 B
    __shared__ float  Tq[NQB];
    __shared__ int    cnt[NQB];
    __shared__ int    cnt2[NQB];

    const int t    = threadIdx.x;
    const int lane = t & 63;
    const int wv   = t >> 6;          // wave 0..7
    const int c    = t >> 1;          // chunk 0..255
    const int qh   = t & 1;           // query group 0..1
    const int xr   = c & 7;           // read-order stagger (JPW=8)
    const int qbase = blockIdx.x * NQB + qh * QPL;

    if (t < NQB) { cnt[t] = 0; cnt2[t] = 0; }

    // Register tile: 8 queries per lane. Fast path: folded -2*q coords, qn
    // omitted inside the min (constant per query, re-added once).
    float qx2[QPL], qy2[QPL], qz2[QPL], qn[QPL];
#pragma unroll
    for (int i = 0; i < QPL; ++i) {
        const float x = verts[(qbase + i) * 3 + 0];
        const float y = verts[(qbase + i) * 3 + 1];
        const float z = verts[(qbase + i) * 3 + 2];
        qn[i] = norm3(x, y, z);
        qx2[i] = -2.0f * x; qy2[i] = -2.0f * y; qz2[i] = -2.0f * z;
    }

    // Issue-early / commit-late staging, vectorized: thread t stages points
    // 4t..4t+3 of the window as 3x float4 (48B, 16B-aligned since 48 | offset).
    float4 f0, f1, f2;
    auto issue = [&](int w) {
        const float4* vv = (const float4*)verts + (w * (WIN / 4) * 3 + 3 * t);
        f0 = vv[0]; f1 = vv[1]; f2 = vv[2];
    };
    auto commit = [&]() {
        const int m = 4 * t;
        pts[m + 0] = make_float4(f0.x, f0.y, f0.z, norm3(f0.x, f0.y, f0.z));
        pts[m + 1] = make_float4(f0.w, f1.x, f1.y, norm3(f0.w, f1.x, f1.y));
        pts[m + 2] = make_float4(f1.z, f1.w, f2.x, norm3(f1.z, f1.w, f2.x));
        pts[m + 3] = make_float4(f2.y, f2.z, f2.w, norm3(f2.y, f2.z, f2.w));
    };

    // ---------------- PASS 1: per-(chunk,query) MIN (shifted fast dist) -----
    // Chunk c's point set: { w*WIN + c*JPW + j : w in [0,NWIN), j in [0,JPW) }.
    float mn[QPL];
#pragma unroll
    for (int i = 0; i < QPL; ++i) mn[i] = INFINITY;

    issue(0); commit(); __syncthreads();
#pragma unroll 1
    for (int w = 0; w < NWIN; ++w) {
        if (w + 1 < NWIN) issue(w + 1);
#pragma unroll
        for (int v = 0; v < JPW; ++v) {
            const float4 p = pts[c * JPW + (v ^ xr)];
#pragma unroll
            for (int i = 0; i < QPL; ++i) {
                const float d = __builtin_fmaf(p.x, qx2[i],
                                __builtin_fmaf(p.y, qy2[i],
                                __builtin_fmaf(p.z, qz2[i], p.w)));
                mn[i] = fminf(mn[i], d);
            }
        }
        __syncthreads();
        if (w + 1 < NWIN) { commit(); __syncthreads(); }
    }

    // Re-add qn so vdump holds true fast distances.
#pragma unroll
    for (int i = 0; i < QPL; ++i) {
        mn[i] += qn[i];
        vdump[c][qh * QPL + i] = mn[i];
    }
    __syncthreads();

    // ------- T' = 20th smallest of 256 chunk-minima + margin ----------------
    // Wave wv handles queries {2wv, 2wv+1}: 256-elem bitonic, 4 regs/lane
    // (element index = lane*4 + reg; verified R7/R11).
#pragma unroll
    for (int r = 0; r < 2; ++r) {
        const int qq = wv * 2 + r;
        float r0 = vdump[lane * 4 + 0][qq];
        float r1 = vdump[lane * 4 + 1][qq];
        float r2 = vdump[lane * 4 + 2][qq];
        float r3 = vdump[lane * 4 + 3][qq];
        { const float lo = fminf(r0, r1), hi = fmaxf(r0, r1); r0 = lo; r1 = hi; }
        { const float lo = fminf(r2, r3), hi = fmaxf(r2, r3); r2 = hi; r3 = lo; }
#pragma unroll
        for (int k = 4; k <= 256; k <<= 1) {
            const bool asc = (((lane << 2) & k) == 0);
#pragma unroll
            for (int j = k >> 1; j >= 4; j >>= 1) {
                const int lj = j >> 2;
                const bool lower = ((lane & lj) == 0);
                const bool keepmin = (lower == asc);
                const float o0 = __shfl_xor(r0, lj), o1 = __shfl_xor(r1, lj);
                const float o2 = __shfl_xor(r2, lj), o3 = __shfl_xor(r3, lj);
                r0 = keepmin ? fminf(r0, o0) : fmaxf(r0, o0);
                r1 = keepmin ? fminf(r1, o1) : fmaxf(r1, o1);
                r2 = keepmin ? fminf(r2, o2) : fmaxf(r2, o2);
                r3 = keepmin ? fminf(r3, o3) : fmaxf(r3, o3);
            }
            {   // j = 2
                const float lo0 = fminf(r0, r2), hi0 = fmaxf(r0, r2);
                const float lo1 = fminf(r1, r3), hi1 = fmaxf(r1, r3);
                r0 = asc ? lo0 : hi0; r2 = asc ? hi0 : lo0;
                r1 = asc ? lo1 : hi1; r3 = asc ? hi1 : lo1;
            }
            {   // j = 1
                const float lo0 = fminf(r0, r1), hi0 = fmaxf(r0, r1);
                const float lo1 = fminf(r2, r3), hi1 = fmaxf(r2, r3);
                r0 = asc ? lo0 : hi0; r1 = asc ? hi0 : lo0;
                r2 = asc ? lo1 : hi1; r3 = asc ? hi1 : lo1;
            }
        }
        const float T = __shfl(r3, 4);          // element 19 = lane 4, reg 3
        if (lane == 0) Tq[qq] = T + MARGIN;
    }
    __syncthreads();

    // ------- Candidate chunks ------------------------------------------------
#pragma unroll
    for (int i = 0; i < QPL; ++i) {
        const int q = qh * QPL + i;
        if (mn[i] <= Tq[q]) {
            const int e = atomicAdd(&cnt2[q], 1);
            if (e < MAXC) cand[q][e] = c;
        }
    }
    __syncthreads();

    // ------- PASS 2 (sparse, fused 2 queries/wave, 4-deep pipeline) ---------
    // Half-wave = one query: lanes 0-31 -> q=2wv, lanes 32-63 -> q=2wv+1.
    // Within a half-wave, 32 lanes = one candidate chunk's 32 points:
    // p = lane&31, n = (p>>3)*WIN + cc*JPW + (p&7).
    {
        const int qq = wv * 2 + (lane >> 5);
        const int qg2 = blockIdx.x * NQB + qq;
        const float qxe = verts[qg2 * 3 + 0];
        const float qye = verts[qg2 * 3 + 1];
        const float qze = verts[qg2 * 3 + 2];
        const float qne = norm3(qxe, qye, qze);
        const float T = Tq[qq];
        const int ncq = min(cnt2[qq], MAXC);
        const int ncm = max(min(cnt2[wv * 2], MAXC), min(cnt2[wv * 2 + 1], MAXC));
        const int p = lane & 31;
        const int nfix = (p >> 3) * WIN + (p & 7);
        for (int e0 = 0; e0 < ncm; e0 += 4) {   // wave-uniform groups of 4
            float PX[4], PY[4], PZ[4]; int NN[4];
#pragma unroll
            for (int u = 0; u < 4; ++u) {       // 12 independent loads in flight
                const int e = e0 + u;
                const int cc = cand[qq][e < ncq ? e : 0];
                const int n = nfix + cc * JPW;
                NN[u] = n;
                PX[u] = verts[n * 3 + 0];
                PY[u] = verts[n * 3 + 1];
                PZ[u] = verts[n * 3 + 2];
            }
#pragma unroll
            for (int u = 0; u < 4; ++u) {
                if (e0 + u < ncq) {
                    const float pw = norm3(PX[u], PY[u], PZ[u]);
                    const float d = dist_exact(PX[u], PY[u], PZ[u], pw,
                                               qxe, qye, qze, qne);
                    if (d <= T) {               // ~25 hits/query total
                        const int slot = atomicAdd(&cnt[qq], 1);
                        if (slot < CAP) { hbd[qq][slot] = d; hbi[qq][slot] = NN[u]; }
                    }
                }
            }
        }
    }
    __syncthreads();

    // ------- Final: exact stable top-20 via u64 bitonic ---------------------
#pragma unroll
    for (int r = 0; r < 2; ++r) {
        const int qq = wv * 2 + r;
        const int kc = min(cnt[qq], CAP);       // kc >= 20 guaranteed
        unsigned long long key = ~0ULL;
        if (lane < kc) {
            const float d = hbd[qq][lane];
            unsigned u = __float_as_uint(d);
            u ^= ((unsigned)((int)u >> 31)) | 0x80000000u;   // order-preserving map
            key = ((unsigned long long)u << 32) | (unsigned)hbi[qq][lane];
        }
#pragma unroll
        for (int k = 2; k <= 64; k <<= 1) {
#pragma unroll
            for (int j = k >> 1; j >= 1; j >>= 1) {
                const unsigned long long o = __shfl_xor(key, j);
                const bool asc = ((lane & k) == 0);
                const bool lower = ((lane & j) == 0);
                const bool keepmin = (lower == asc);
                const bool lt = key < o;
                key = (keepmin == lt) ? key : o;
            }
        }
        if (lane < KK)
            out[(blockIdx.x * NQB + qq) * KK + lane] =
                (int)(unsigned)(key & 0xffffffffULL);
    }
}

extern "C" void kernel_launch(void* const* d_in, const int* in_sizes, int n_in,
                              void* d_out, int out_size, void* d_ws, size_t ws_size,
                              hipStream_t stream) {
    // d_in[0] = feats (unused). d_in[1] = vertices [4,8192,3] f32; batch 0 only.
    const float* verts = (const float*)d_in[1];
    int* out = (int*)d_out;
    knn_kernel<<<dim3(NPTS / NQB), dim3(THREADS), 0, stream>>>(verts, out);
}